// Round 11
// baseline (349.092 us; speedup 1.0000x reference)
//
#include <hip/hip_runtime.h>
#include <hip/hip_bf16.h>

// LSTM B=8192,T=512,I=3,H=25 + linear[H->1], bf16 MFMA 16x16x32.
// R23: ONE WAVE PER SIMD, TWO CHAINS PER WAVE. Phase-engineering (R21/R22)
// is dead: in-phase co-residents are a stable attractor (lagging wave gets
// uncontended issue, speeds up, re-locks). Design rule from R12-R22:
// exactly 1 wave/SIMD, with INTRA-WAVE independent work covering the
// read->MFMA->acts chain. Block = 4 waves (1/SIMD) = 2 chains (32 batches);
// each wave runs the R19 per-chain step twice back-to-back (chain0, chain1)
// per barrier interval: chain1's 224cy trans stream covers chain0's chain
// tail and vice versa - overlap inside ONE instruction stream, no luck.
// R13 failed this idea only because 7 waves on 4 SIMDs put 2 in-phase
// siblings per SIMD (issue doubled); here grid=256 blocks + 90KB dynamic
// LDS force exactly 1 block/CU, 1 wave/SIMD.
// Model: interval = prefix ~130 + 28 trans x 16 (448) + glue ~80 + barrier
// ~40 = ~700cy for TWO chain-steps (vs 914 for one today) -> ~150us.
// Kept from R19: register A-frags with -K1/-K2 prescale (shared by both
// chains), x-insert from registers (q0 lanes), frag-linear LDS, pad/scrap
// slot writes, merged-denominator c-update, v2f pk glue across row-blocks,
// lgkmcnt-only barrier (x prefetch stays in flight).

#define TSTEPS 512
#define ISZ 3
#define HSZ 25

typedef __attribute__((ext_vector_type(8))) short bf16x8;
typedef __attribute__((ext_vector_type(4))) float f32x4;
typedef __attribute__((ext_vector_type(4))) int i32x4;
typedef __attribute__((ext_vector_type(2))) float v2f;

__device__ __forceinline__ unsigned short bf16_bits(float v) {
    return __builtin_bit_cast(unsigned short, __float2bfloat16(v));
}
__device__ __forceinline__ unsigned int pack_bf16(float lo, float hi) {
    return ((unsigned int)bf16_bits(hi) << 16) | (unsigned int)bf16_bits(lo);
}
__device__ __forceinline__ v2f rcp2(v2f v) {
    return (v2f){__builtin_amdgcn_rcpf(v.x), __builtin_amdgcn_rcpf(v.y)};
}

__global__ __launch_bounds__(256, 1) void lstm_mfma(
    const float* __restrict__ x,      // [B, T, I]
    const float* __restrict__ w_ih,   // [4H, I]
    const float* __restrict__ w_hh,   // [4H, H]
    const float* __restrict__ b_ih,   // [4H]
    const float* __restrict__ b_hh,   // [4H]
    const float* __restrict__ w_lin,  // [1, H]
    const float* __restrict__ b_lin,  // [1]
    float* __restrict__ out)          // [B, 1]
{
    // frag-linear: short idx (k,n) = (k>>3)*128 + n*8 + (k&7); idx 0..511 is
    // the real frag (k<32); 512..767 scrap for row-block-7 writes (kw<=35).
    __shared__ short hb[2][2][768];       // [chain][parity]
    __shared__ float outred[4][2][16];

    const int tid  = threadIdx.x;
    const int w    = tid >> 6;        // wave 0..3, one per SIMD
    const int lane = tid & 63;
    const int n    = lane & 15;       // batch col within chain
    const int q    = lane >> 4;       // quad -> k-slots 8q..8q+7
    const int b0   = blockIdx.x * 32;

    const float K1 = 1.442695040888963f;   // log2 e
    const float K2 = 2.885390081777927f;   // 2 log2 e

    // zero both chains' parity buffers (h(0)=0): 6144 B
    for (int i = tid; i < 384; i += 256) ((int4*)hb)[i] = (int4){0, 0, 0, 0};

    // ---- A fragments for row-blocks jbA=w, jbB=w+4 (shared by chains) ----
    // Within a row-block: MFMA row rr=n -> unit 4*jb + (n>>2), gate n&3.
    // k map: 0..2 w_ih, 3 bias, 4..28 w_hh col k-4, 29..31 pad.
    bf16x8 afA, afB;
    {
        const int g = n & 3, us = n >> 2;
        const int uA = 4 * w + us;            // <= 15, always valid
        const int uB = 4 * (w + 4) + us;      // 16..31, guard < 25
        #pragma unroll
        for (int j = 0; j < 8; ++j) {
            const int k = q * 8 + j;
            float vA = 0.f, vB = 0.f;
            {
                const int orow = g * HSZ + uA;
                if (k < ISZ)            vA = w_ih[orow * ISZ + k];
                else if (k == ISZ)      vA = b_ih[orow] + b_hh[orow];
                else if (k < 4 + HSZ)   vA = w_hh[orow * HSZ + (k - 4)];
                vA *= (g == 2) ? -K2 : -K1;
            }
            if (uB < HSZ) {
                const int orow = g * HSZ + uB;
                if (k < ISZ)            vB = w_ih[orow * ISZ + k];
                else if (k == ISZ)      vB = b_ih[orow] + b_hh[orow];
                else if (k < 4 + HSZ)   vB = w_hh[orow * HSZ + (k - 4)];
                vB *= (g == 2) ? -K2 : -K1;
            }
            afA[j] = (short)bf16_bits(vA);
            afB[j] = (short)bf16_bits(vB);
        }
    }

    // ---- write slots: unit u=4jb+q -> k=u+4 (pads/scrap land harmlessly) --
    const int uwA = 4 * w + q;                 // <= 15
    const int uwB = 4 * (w + 4) + q;           // 16..31 (>=25 -> pad/scrap)
    const int kwA = uwA + 4, kwB = uwB + 4;    // kwB <= 35 -> scrap region
    const int woffA = (kwA >> 3) * 128 + n * 8 + (kwA & 7);
    const int woffB = (kwB >> 3) * 128 + n * 8 + (kwB & 7);
    const int rdoff = lane * 8;

    v2f c0 = {0.f, 0.f}, h0 = {0.f, 0.f};      // chain 0 state (rbA, rbB)
    v2f c1 = {0.f, 0.f}, h1 = {0.f, 0.f};      // chain 1 state

    // ---- x prefetch: per chain 3 x float4 per 4-step group ----
    const float* __restrict__ xg0 = x + (size_t)(b0 + n) * (TSTEPS * ISZ);
    const float* __restrict__ xg1 = x + (size_t)(b0 + 16 + n) * (TSTEPS * ISZ);
    float4 A0 = ((const float4*)xg0)[0];
    float4 A1 = ((const float4*)xg0)[1];
    float4 A2 = ((const float4*)xg0)[2];
    float4 B0 = ((const float4*)xg1)[0];
    float4 B1 = ((const float4*)xg1)[1];
    float4 B2 = ((const float4*)xg1)[2];

    __syncthreads();   // zeros visible (drains first prefetch once - ok)

    // one chain's step: read frag, 2 MFMAs, acts (v2f across row-blocks),
    // write h to its buffer. Identical math to R19 (passed, absmax .0156).
    auto chainstep = [&](short (&buf)[2][768], int rp, v2f& c, v2f& h,
                         float x0, float x1, float x2) {
        bf16x8 frag = *(const bf16x8*)&buf[rp][rdoff];
        i32x4 fi = __builtin_bit_cast(i32x4, frag);
        const int px0 = (int)pack_bf16(x0, x1);
        const int px1 = (int)pack_bf16(x2, 1.0f);
        fi[0] = (q == 0) ? px0 : fi[0];
        fi[1] = (q == 0) ? px1 : fi[1];
        frag = __builtin_bit_cast(bf16x8, fi);

        const f32x4 zc = {0.f, 0.f, 0.f, 0.f};
        const f32x4 aA = __builtin_amdgcn_mfma_f32_16x16x32_bf16(afA, frag, zc, 0, 0, 0);
        const f32x4 aB = __builtin_amdgcn_mfma_f32_16x16x32_bf16(afB, frag, zc, 0, 0, 0);

        const v2f e0 = {__builtin_amdgcn_exp2f(aA[0]), __builtin_amdgcn_exp2f(aB[0])};
        const v2f e1 = {__builtin_amdgcn_exp2f(aA[1]), __builtin_amdgcn_exp2f(aB[1])};
        const v2f e2 = {__builtin_amdgcn_exp2f(fminf(aA[2], 126.f)),
                        __builtin_amdgcn_exp2f(fminf(aB[2], 126.f))};
        const v2f e3 = {__builtin_amdgcn_exp2f(aA[3]), __builtin_amdgcn_exp2f(aB[3])};
        const v2f one = {1.f, 1.f};
        const v2f s0 = e0 + one, s1 = e1 + one, s2 = e2 + one, m2 = one - e2;
        const v2f p02 = s0 * s2;
        const v2f num = c * p02 + m2 * s1;     // merged-denominator c-update
        const v2f den = p02 * s1;
        c = num * rcp2(den);
        const v2f ec = {__builtin_amdgcn_exp2f(fminf(-K2 * c.x, 126.f)),
                        __builtin_amdgcn_exp2f(fminf(-K2 * c.y, 126.f))};
        const v2f hden = (e3 + one) * (ec + one);
        h = (one - ec) * rcp2(hden);

        const int wp = rp ^ 1;
        buf[wp][woffA] = (short)bf16_bits(h.x);
        buf[wp][woffB] = (short)bf16_bits(h.y);   // pad/scrap-slot trick
    };

    // one interval: both chains advance one step, ONE barrier.
    auto step2 = [&](int rp, float ax0, float ax1, float ax2,
                     float bx0, float bx1, float bx2) {
        chainstep(hb[0], rp, c0, h0, ax0, ax1, ax2);
        chainstep(hb[1], rp, c1, h1, bx0, bx1, bx2);
        // retire DS writes, then barrier; vmcnt (x prefetch) stays in flight
        asm volatile("s_waitcnt lgkmcnt(0)" ::: "memory");
        __builtin_amdgcn_s_barrier();
    };

    #pragma unroll 1
    for (int g = 0; g < 128; g += 2) {
        const int gp1 = (g + 1 < 128) ? g + 1 : 127;
        const float4* __restrict__ pA1 = (const float4*)(xg0 + (size_t)gp1 * 12);
        const float4* __restrict__ pB1 = (const float4*)(xg1 + (size_t)gp1 * 12);
        const float4 nA0 = pA1[0], nA1 = pA1[1], nA2 = pA1[2];
        const float4 nB0 = pB1[0], nB1 = pB1[1], nB2 = pB1[2];
        step2(0, A0.x, A0.y, A0.z, B0.x, B0.y, B0.z);
        step2(1, A0.w, A1.x, A1.y, B0.w, B1.x, B1.y);
        step2(0, A1.z, A1.w, A2.x, B1.z, B1.w, B2.x);
        step2(1, A2.y, A2.z, A2.w, B2.y, B2.z, B2.w);
        const int gp2 = (g + 2 < 128) ? g + 2 : 127;
        const float4* __restrict__ pA2 = (const float4*)(xg0 + (size_t)gp2 * 12);
        const float4* __restrict__ pB2 = (const float4*)(xg1 + (size_t)gp2 * 12);
        A0 = pA2[0]; A1 = pA2[1]; A2 = pA2[2];
        B0 = pB2[0]; B1 = pB2[1]; B2 = pB2[2];
        step2(0, nA0.x, nA0.y, nA0.z, nB0.x, nB0.y, nB0.z);
        step2(1, nA0.w, nA1.x, nA1.y, nB0.w, nB1.x, nB1.y);
        step2(0, nA1.z, nA1.w, nA2.x, nB1.z, nB1.w, nB2.x);
        step2(1, nA2.y, nA2.z, nA2.w, nB2.y, nB2.z, nB2.w);
    }

    // ---- final linear: out[b] = sum_u w_lin[u]*h[u] + b_lin, per chain ----
    const float wlA = (uwA < HSZ) ? w_lin[uwA] : 0.f;
    const float wlB = (uwB < HSZ) ? w_lin[uwB] : 0.f;
    float v0 = wlA * h0.x + wlB * h0.y;
    float v1 = wlA * h1.x + wlB * h1.y;
    v0 += __shfl_xor(v0, 16);
    v1 += __shfl_xor(v1, 16);
    v0 += __shfl_xor(v0, 32);
    v1 += __shfl_xor(v1, 32);
    if (lane < 16) {
        outred[w][0][lane] = v0;
        outred[w][1][lane] = v1;
    }
    __syncthreads();
    if (tid < 32) {
        const int c2 = tid >> 4, nn = tid & 15;
        float s = b_lin[0];
        #pragma unroll
        for (int k2 = 0; k2 < 4; ++k2) s += outred[k2][c2][nn];
        out[b0 + c2 * 16 + nn] = s;
    }
}

extern "C" void kernel_launch(void* const* d_in, const int* in_sizes, int n_in,
                              void* d_out, int out_size, void* d_ws, size_t ws_size,
                              hipStream_t stream) {
    const float* x     = (const float*)d_in[0];
    const float* w_ih  = (const float*)d_in[1];
    const float* w_hh  = (const float*)d_in[2];
    const float* b_ih  = (const float*)d_in[3];
    const float* b_hh  = (const float*)d_in[4];
    const float* w_lin = (const float*)d_in[5];
    const float* b_lin = (const float*)d_in[6];
    float* out = (float*)d_out;

    // 90 KB dynamic LDS (unused) + ~6.7 KB static -> only 1 block/CU fits:
    // guarantees 1 wave/SIMD, no co-resident block, no phase lottery.
    lstm_mfma<<<8192 / 32, 256, 90 * 1024, stream>>>(x, w_ih, w_hh, b_ih, b_hh,
                                                     w_lin, b_lin, out);
}

// Round 12
// 302.842 us; speedup vs baseline: 1.1527x; 1.1527x over previous
//
#include <hip/hip_runtime.h>
#include <hip/hip_bf16.h>

// LSTM B=8192,T=512,I=3,H=25 + linear[H->1], bf16 MFMA 16x16x32.
// R24: ROTATED DUAL-PHASE - structural anti-phase, 2 barriers/step.
// R23 post-mortem: compiler-driven intra-wave ILP is dead (3 strikes:
// R16/R17/R23 - regalloc serializes); scheduler-driven overlap between
// waves is real but partial (R19's 2 blocks half-overlap: exposed 394 vs
// R23's 770 at 1 block/CU). This kernel makes the overlap STRUCTURAL:
// one 512-thread block/CU; waves 0-3 = chain A, waves 4-7 = chain B, so
// each SIMD hosts one A-wave + one B-wave. Two barriers per step, B's
// schedule rotated one phase:
//   phase1: A {read fragA(t), x-insert, 2 MFMA}   (~40cy issue, latency)
//           B {acts of B(t-1) from reg acc, write h_B(t)} (~285cy trans)
//   phase2: roles swapped.
// Per phase the SIMD trans pipe gets exactly one acts burst while the
// partner's read/MFMA latency runs underneath - complementary by code
// layout, immune to phase drift, no compiler ILP needed (acc crosses the
// barrier in 8 VGPRs). Rotation needs no prologue: acts on zero acc and
// zero c yields exactly h=0 (buffer pre-zeroed); B runs one extra acts
// after the loop. Single buffer/chain (2nd barrier separates read/write).
// Kept: reg A-frags w/ -K1/-K2 prescale, frag-linear LDS, pad/scrap-slot
// writes, merged-denominator c-update, v2f pk glue, x reg ping-pong,
// lgkmcnt-only barrier (vmcnt prefetch stays in flight).

#define TSTEPS 512
#define ISZ 3
#define HSZ 25

typedef __attribute__((ext_vector_type(8))) short bf16x8;
typedef __attribute__((ext_vector_type(4))) float f32x4;
typedef __attribute__((ext_vector_type(4))) int i32x4;
typedef __attribute__((ext_vector_type(2))) float v2f;

__device__ __forceinline__ unsigned short bf16_bits(float v) {
    return __builtin_bit_cast(unsigned short, __float2bfloat16(v));
}
__device__ __forceinline__ unsigned int pack_bf16(float lo, float hi) {
    return ((unsigned int)bf16_bits(hi) << 16) | (unsigned int)bf16_bits(lo);
}
__device__ __forceinline__ v2f rcp2(v2f v) {
    return (v2f){__builtin_amdgcn_rcpf(v.x), __builtin_amdgcn_rcpf(v.y)};
}

__global__ __launch_bounds__(512, 1) void lstm_mfma(
    const float* __restrict__ x,      // [B, T, I]
    const float* __restrict__ w_ih,   // [4H, I]
    const float* __restrict__ w_hh,   // [4H, H]
    const float* __restrict__ b_ih,   // [4H]
    const float* __restrict__ b_hh,   // [4H]
    const float* __restrict__ w_lin,  // [1, H]
    const float* __restrict__ b_lin,  // [1]
    float* __restrict__ out)          // [B, 1]
{
    // frag-linear per chain: short idx (k,n) = (k>>3)*128 + n*8 + (k&7);
    // 0..511 real frag (k<32); 512..767 scrap for row-block-7 (kw<=35).
    __shared__ short hb[2][768];          // [chain], single buffer
    __shared__ float outred[8][16];

    const int tid  = threadIdx.x;
    const int w    = tid >> 6;        // wave 0..7
    const int lane = tid & 63;
    const int n    = lane & 15;       // batch col within chain
    const int q    = lane >> 4;       // quad -> k-slots 8q..8q+7
    const int ch   = w >> 2;          // 0 = chain A group, 1 = chain B group
    const int wv   = w & 3;           // row-block set within chain
    const int b0   = blockIdx.x * 32;

    const float K1 = 1.442695040888963f;   // log2 e
    const float K2 = 2.885390081777927f;   // 2 log2 e

    // zero both chains' buffers (h(0)=0): 3072 B
    if (tid < 192) ((int4*)hb)[tid] = (int4){0, 0, 0, 0};

    // ---- A fragments for row-blocks jbA=wv, jbB=wv+4 ----
    // Within a row-block: MFMA row rr=n -> unit 4*jb + (n>>2), gate n&3.
    // k map: 0..2 w_ih, 3 bias, 4..28 w_hh col k-4, 29..31 pad.
    bf16x8 afA, afB;
    {
        const int g = n & 3, us = n >> 2;
        const int uA = 4 * wv + us;           // <= 15, always valid
        const int uB = 4 * (wv + 4) + us;     // 16..31, guard < 25
        #pragma unroll
        for (int j = 0; j < 8; ++j) {
            const int k = q * 8 + j;
            float vA = 0.f, vB = 0.f;
            {
                const int orow = g * HSZ + uA;
                if (k < ISZ)            vA = w_ih[orow * ISZ + k];
                else if (k == ISZ)      vA = b_ih[orow] + b_hh[orow];
                else if (k < 4 + HSZ)   vA = w_hh[orow * HSZ + (k - 4)];
                vA *= (g == 2) ? -K2 : -K1;
            }
            if (uB < HSZ) {
                const int orow = g * HSZ + uB;
                if (k < ISZ)            vB = w_ih[orow * ISZ + k];
                else if (k == ISZ)      vB = b_ih[orow] + b_hh[orow];
                else if (k < 4 + HSZ)   vB = w_hh[orow * HSZ + (k - 4)];
                vB *= (g == 2) ? -K2 : -K1;
            }
            afA[j] = (short)bf16_bits(vA);
            afB[j] = (short)bf16_bits(vB);
        }
    }

    // ---- write slots: unit u=4jb+q -> k=u+4 (pads/scrap land harmlessly) --
    const int uwA = 4 * wv + q;                // <= 15
    const int uwB = 4 * (wv + 4) + q;          // 16..31 (>=25 -> pad/scrap)
    const int kwA = uwA + 4, kwB = uwB + 4;    // kwB <= 35 -> scrap region
    const int woffA = (kwA >> 3) * 128 + n * 8 + (kwA & 7);
    const int woffB = (kwB >> 3) * 128 + n * 8 + (kwB & 7);
    const int rdoff = lane * 8;

    v2f c = {0.f, 0.f}, h = {0.f, 0.f};
    f32x4 accA = {0.f, 0.f, 0.f, 0.f};    // persists across barriers
    f32x4 accB = {0.f, 0.f, 0.f, 0.f};

    // ---- x prefetch for this wave's chain: 3 x float4 per 4-step group ----
    const float* __restrict__ xg =
        x + (size_t)(b0 + ch * 16 + n) * (TSTEPS * ISZ);
    float4 a0 = ((const float4*)xg)[0];
    float4 a1 = ((const float4*)xg)[1];
    float4 a2 = ((const float4*)xg)[2];

    __syncthreads();   // zeros visible (drains first prefetch once - ok)

    // read frag of own chain, insert x, 2 MFMAs -> acc (kept in regs)
    auto mfmaP = [&](float x0, float x1, float x2) {
        bf16x8 frag = *(const bf16x8*)&hb[ch][rdoff];
        i32x4 fi = __builtin_bit_cast(i32x4, frag);
        const int px0 = (int)pack_bf16(x0, x1);
        const int px1 = (int)pack_bf16(x2, 1.0f);
        fi[0] = (q == 0) ? px0 : fi[0];
        fi[1] = (q == 0) ? px1 : fi[1];
        frag = __builtin_bit_cast(bf16x8, fi);
        const f32x4 zc = {0.f, 0.f, 0.f, 0.f};
        accA = __builtin_amdgcn_mfma_f32_16x16x32_bf16(afA, frag, zc, 0, 0, 0);
        accB = __builtin_amdgcn_mfma_f32_16x16x32_bf16(afB, frag, zc, 0, 0, 0);
    };

    // acts on held acc -> update c,h; write h to own chain's buffer
    auto actsP = [&]() {
        const v2f e0 = {__builtin_amdgcn_exp2f(accA[0]), __builtin_amdgcn_exp2f(accB[0])};
        const v2f e1 = {__builtin_amdgcn_exp2f(accA[1]), __builtin_amdgcn_exp2f(accB[1])};
        const v2f e2 = {__builtin_amdgcn_exp2f(fminf(accA[2], 126.f)),
                        __builtin_amdgcn_exp2f(fminf(accB[2], 126.f))};
        const v2f e3 = {__builtin_amdgcn_exp2f(accA[3]), __builtin_amdgcn_exp2f(accB[3])};
        const v2f one = {1.f, 1.f};
        const v2f s0 = e0 + one, s1 = e1 + one, s2 = e2 + one, m2 = one - e2;
        const v2f p02 = s0 * s2;
        const v2f num = c * p02 + m2 * s1;     // merged-denominator c-update
        const v2f den = p02 * s1;
        c = num * rcp2(den);
        const v2f ec = {__builtin_amdgcn_exp2f(fminf(-K2 * c.x, 126.f)),
                        __builtin_amdgcn_exp2f(fminf(-K2 * c.y, 126.f))};
        const v2f hden = (e3 + one) * (ec + one);
        h = (one - ec) * rcp2(hden);
        hb[ch][woffA] = (short)bf16_bits(h.x);
        hb[ch][woffB] = (short)bf16_bits(h.y);   // pad/scrap-slot trick
    };

    auto bar = [&]() {
        asm volatile("s_waitcnt lgkmcnt(0)" ::: "memory");
        __builtin_amdgcn_s_barrier();
    };

    if (ch == 0) {
        // chain A schedule: [read+MFMA] bar [acts+write] bar
        #pragma unroll 1
        for (int g = 0; g < 128; g += 2) {
            const int gp1 = (g + 1 < 128) ? g + 1 : 127;
            const float4* __restrict__ p1 = (const float4*)(xg + (size_t)gp1 * 12);
            const float4 n0 = p1[0], n1 = p1[1], n2 = p1[2];
            mfmaP(a0.x, a0.y, a0.z); bar(); actsP(); bar();
            mfmaP(a0.w, a1.x, a1.y); bar(); actsP(); bar();
            mfmaP(a1.z, a1.w, a2.x); bar(); actsP(); bar();
            mfmaP(a2.y, a2.z, a2.w); bar(); actsP(); bar();
            const int gp2 = (g + 2 < 128) ? g + 2 : 127;
            const float4* __restrict__ p2 = (const float4*)(xg + (size_t)gp2 * 12);
            a0 = p2[0]; a1 = p2[1]; a2 = p2[2];
            mfmaP(n0.x, n0.y, n0.z); bar(); actsP(); bar();
            mfmaP(n0.w, n1.x, n1.y); bar(); actsP(); bar();
            mfmaP(n1.z, n1.w, n2.x); bar(); actsP(); bar();
            mfmaP(n2.y, n2.z, n2.w); bar(); actsP(); bar();
        }
    } else {
        // chain B schedule (rotated): [acts+write of t-1] bar [read+MFMA] bar
        // first acts runs on zero acc/zero c -> writes exact h=0 (harmless).
        #pragma unroll 1
        for (int g = 0; g < 128; g += 2) {
            const int gp1 = (g + 1 < 128) ? g + 1 : 127;
            const float4* __restrict__ p1 = (const float4*)(xg + (size_t)gp1 * 12);
            const float4 n0 = p1[0], n1 = p1[1], n2 = p1[2];
            actsP(); bar(); mfmaP(a0.x, a0.y, a0.z); bar();
            actsP(); bar(); mfmaP(a0.w, a1.x, a1.y); bar();
            actsP(); bar(); mfmaP(a1.z, a1.w, a2.x); bar();
            actsP(); bar(); mfmaP(a2.y, a2.z, a2.w); bar();
            const int gp2 = (g + 2 < 128) ? g + 2 : 127;
            const float4* __restrict__ p2 = (const float4*)(xg + (size_t)gp2 * 12);
            a0 = p2[0]; a1 = p2[1]; a2 = p2[2];
            actsP(); bar(); mfmaP(n0.x, n0.y, n0.z); bar();
            actsP(); bar(); mfmaP(n0.w, n1.x, n1.y); bar();
            actsP(); bar(); mfmaP(n1.z, n1.w, n2.x); bar();
            actsP(); bar(); mfmaP(n2.y, n2.z, n2.w); bar();
        }
        actsP();   // finish step 511 -> h_B(512) (write harmless, no barrier)
    }

    // ---- final linear: out[b] = sum_u w_lin[u]*h[u] + b_lin, per chain ----
    const float wlA = (uwA < HSZ) ? w_lin[uwA] : 0.f;
    const float wlB = (uwB < HSZ) ? w_lin[uwB] : 0.f;
    float v = wlA * h.x + wlB * h.y;
    v += __shfl_xor(v, 16);
    v += __shfl_xor(v, 32);
    if (lane < 16) outred[w][lane] = v;
    __syncthreads();
    if (tid < 32) {
        const int c2 = tid >> 4, nn = tid & 15;
        float s = b_lin[0];
        #pragma unroll
        for (int k2 = 0; k2 < 4; ++k2) s += outred[c2 * 4 + k2][nn];
        out[b0 + c2 * 16 + nn] = s;
    }
}

extern "C" void kernel_launch(void* const* d_in, const int* in_sizes, int n_in,
                              void* d_out, int out_size, void* d_ws, size_t ws_size,
                              hipStream_t stream) {
    const float* x     = (const float*)d_in[0];
    const float* w_ih  = (const float*)d_in[1];
    const float* w_hh  = (const float*)d_in[2];
    const float* b_ih  = (const float*)d_in[3];
    const float* b_hh  = (const float*)d_in[4];
    const float* w_lin = (const float*)d_in[5];
    const float* b_lin = (const float*)d_in[6];
    float* out = (float*)d_out;

    lstm_mfma<<<8192 / 32, 512, 0, stream>>>(x, w_ih, w_hh, b_ih, b_hh,
                                             w_lin, b_lin, out);
}